// Round 1
// 1260.803 us; speedup vs baseline: 1.0514x; 1.0514x over previous
//
#include <hip/hip_runtime.h>
#include <hip/hip_bf16.h>

// ---------------- problem constants ----------------
#define T_TOK   8192
#define H_DIM   1024
#define FFN_DIM 4096
#define NE      8
#define N13     (2 * FFN_DIM)            // 8192 fused [w1|w3] columns (interleaved)

// gemm2 tile (unchanged this round)
#define BM 128
#define BN 128
#define BK 32

// gemm1 8-phase tile
#define G1_BK   64
#define G1_NKT  (H_DIM / G1_BK)          // 16
#define G1_SMEM (1024 + 131072)          // toks + 2x(A 32KB) + 2x(B 32KB)

#define MAX_RB256 (T_TOK * 2 / 256 + NE) // 72
#define MAX_ROWS  (MAX_RB256 * 256)      // 18432
#define MAX_RB128 (MAX_ROWS / 128)       // 144

typedef unsigned short u16;
typedef unsigned int   u32;
typedef u16   u16x8  __attribute__((ext_vector_type(8)));
typedef __bf16 bf16x8 __attribute__((ext_vector_type(8)));
typedef float f32x4  __attribute__((ext_vector_type(4)));

// ---------------- workspace layout (bytes) ----------------
// meta ints: [0..7] counts, [8..15] fill, [16..24] padded offsets (256-granular),
//            [25] total_rows, [26] rb128 count, [27] rb256 count
#define META_OFF   ((size_t)0)
#define PICKE_OFF  ((size_t)1024)
#define PICKW_OFF  (PICKE_OFF + (size_t)T_TOK * 2 * 4)
#define PERM_OFF   (PICKW_OFF + (size_t)T_TOK * 2 * 4)
#define WSORT_OFF  (PERM_OFF  + (size_t)MAX_ROWS * 4)
#define XBF_OFF    (WSORT_OFF + (size_t)MAX_ROWS * 4)               // 279552
#define W13T_OFF   (XBF_OFF + (size_t)T_TOK * H_DIM * 2)            // +16 MB
#define W2T_OFF    (W13T_OFF + (size_t)NE * N13 * H_DIM * 2)        // +128 MB
#define HBUF_OFF   (W2T_OFF + (size_t)NE * FFN_DIM * H_DIM * 2)     // +64 MB
#define YPART_OFF  W13T_OFF   // alias: w13t (128MB) dead after gemm1; ypart fp32 (67MB)

__device__ __forceinline__ u16 f2bf(float f) {
    unsigned u = __builtin_bit_cast(unsigned, f);
    unsigned r = u + 0x7fffu + ((u >> 16) & 1u);   // RNE
    return (u16)(r >> 16);
}

// async global->LDS, 16B per lane, dest = wave-uniform base + lane*16
__device__ __forceinline__ void gl_lds16(const void* g, void* l) {
    __builtin_amdgcn_global_load_lds((const __attribute__((address_space(1))) u32*)g,
                                     (__attribute__((address_space(3))) u32*)l,
                                     16, 0, 0);
}

// ---------------- tiny init ----------------
__global__ void init_k(int* meta) {
    if (threadIdx.x < 256) meta[threadIdx.x] = 0;
}

// ---------------- x: fp32 -> bf16, same layout ----------------
__global__ void cvt_x_k(const float* __restrict__ src, u16* __restrict__ dst) {
    int i = blockIdx.x * 256 + threadIdx.x;   // one u16x8 per thread
    f32x4 a = *(const f32x4*)(src + (size_t)i * 8);
    f32x4 b = *(const f32x4*)(src + (size_t)i * 8 + 4);
    u16x8 o;
#pragma unroll
    for (int j = 0; j < 4; j++) { o[j] = f2bf(a[j]); o[4 + j] = f2bf(b[j]); }
    *(u16x8*)(dst + (size_t)i * 8) = o;
}

// ---------------- transpose+convert for w2: dst_bf16[C][R] = src_f32[R][C] ----------------
__global__ void transpose_cvt_k(const float* __restrict__ src, u16* __restrict__ dst, int R, int C) {
    __shared__ u16 Lt[64 * 72];
    int bx = blockIdx.x, by = blockIdx.y, e = blockIdx.z;
    const float* s = src + (size_t)e * R * C + (size_t)(by * 64) * C + bx * 64;
    u16* d = dst + (size_t)e * R * C + (size_t)(bx * 64) * R + by * 64;
    int tid = threadIdx.x;
#pragma unroll
    for (int o = tid; o < 512; o += 256) {
        int r = o >> 3, cc = o & 7;
        const float* sp = s + (size_t)r * C + cc * 8;
        f32x4 f0 = *(const f32x4*)sp;
        f32x4 f1 = *(const f32x4*)(sp + 4);
        u16x8 v;
#pragma unroll
        for (int j = 0; j < 4; j++) { v[j] = f2bf(f0[j]); v[4 + j] = f2bf(f1[j]); }
        int cs = (cc ^ ((r >> 3) & 7)) & 7;
        *(u16x8*)&Lt[r * 72 + cs * 8] = v;
    }
    __syncthreads();
#pragma unroll
    for (int o = tid; o < 512; o += 256) {
        int cl = o >> 3, rc = o & 7;
        u16x8 w;
#pragma unroll
        for (int j = 0; j < 8; j++) {
            int rr = rc * 8 + j;
            w[j] = Lt[rr * 72 + ((((cl >> 3) ^ rc) & 7) * 8) + (cl & 7)];
        }
        *(u16x8*)(d + (size_t)cl * R + rc * 8) = w;
    }
}

// ---------------- transpose+convert w1/w3 -> interleaved w13t[e][n'][k] ----------------
// n' layout: per 256-col supertile nb: 4 wave-blocks of 64 = [32 w1-cols | 32 w3-cols]
// n'(c, which) = (c>>7)*256 + ((c>>5)&3)*64 + which*32 + (c&31)
__global__ void transpose_cvt_w13_k(const float* __restrict__ src, u16* __restrict__ dst, int which) {
    __shared__ u16 Lt[64 * 72];
    int bx = blockIdx.x, by = blockIdx.y, e = blockIdx.z;
    const float* s = src + (size_t)e * H_DIM * FFN_DIM + (size_t)(by * 64) * FFN_DIM + bx * 64;
    u16* d = dst + (size_t)e * N13 * H_DIM;
    int tid = threadIdx.x;
#pragma unroll
    for (int o = tid; o < 512; o += 256) {
        int r = o >> 3, cc = o & 7;
        const float* sp = s + (size_t)r * FFN_DIM + cc * 8;
        f32x4 f0 = *(const f32x4*)sp;
        f32x4 f1 = *(const f32x4*)(sp + 4);
        u16x8 v;
#pragma unroll
        for (int j = 0; j < 4; j++) { v[j] = f2bf(f0[j]); v[4 + j] = f2bf(f1[j]); }
        int cs = (cc ^ ((r >> 3) & 7)) & 7;
        *(u16x8*)&Lt[r * 72 + cs * 8] = v;
    }
    __syncthreads();
#pragma unroll
    for (int o = tid; o < 512; o += 256) {
        int cl = o >> 3, rc = o & 7;
        u16x8 w;
#pragma unroll
        for (int j = 0; j < 8; j++) {
            int rr = rc * 8 + j;
            w[j] = Lt[rr * 72 + ((((cl >> 3) ^ rc) & 7) * 8) + (cl & 7)];
        }
        int c = bx * 64 + cl;
        int np = ((c >> 7) << 8) | (((c >> 5) & 3) << 6) | (which << 5) | (c & 31);
        *(u16x8*)(d + (size_t)np * H_DIM + by * 64 + rc * 8) = w;
    }
}

// ---------------- router: fp32 logits, top-2, picks ----------------
__global__ void router_k(const float* __restrict__ x, const float* __restrict__ gw,
                         float* __restrict__ out_logits, int* __restrict__ meta,
                         int* __restrict__ picke, float* __restrict__ pickw) {
    __shared__ float G[NE * H_DIM];   // 32 KB
    int tid = threadIdx.x;
#pragma unroll
    for (int o = tid; o < 2048; o += 256)
        *(f32x4*)&G[o * 4] = *(const f32x4*)(gw + o * 4);
    __syncthreads();

    int wave = tid >> 6, lane = tid & 63;
    int t = blockIdx.x * 4 + wave;
    const float* xr = x + (size_t)t * H_DIM + lane * 16;
    f32x4 v0 = *(const f32x4*)xr,       v1 = *(const f32x4*)(xr + 4);
    f32x4 v2 = *(const f32x4*)(xr + 8), v3 = *(const f32x4*)(xr + 12);

    float acc[NE];
#pragma unroll
    for (int e = 0; e < NE; e++) {
        const float* gr = &G[e * H_DIM + lane * 16];
        f32x4 g0 = *(const f32x4*)gr,       g1 = *(const f32x4*)(gr + 4);
        f32x4 g2 = *(const f32x4*)(gr + 8), g3 = *(const f32x4*)(gr + 12);
        float a = 0.f;
#pragma unroll
        for (int j = 0; j < 4; j++) {
            a += v0[j] * g0[j]; a += v1[j] * g1[j];
            a += v2[j] * g2[j]; a += v3[j] * g3[j];
        }
        acc[e] = a;
    }
#pragma unroll
    for (int e = 0; e < NE; e++)
#pragma unroll
        for (int off = 32; off > 0; off >>= 1) acc[e] += __shfl_xor(acc[e], off);

    if (lane < NE) out_logits[(size_t)t * NE + lane] = acc[lane];
    if (lane == 0) {
        int a1 = 0;
#pragma unroll
        for (int e = 1; e < NE; e++) if (acc[e] > acc[a1]) a1 = e;
        int a2 = (a1 == 0) ? 1 : 0;
#pragma unroll
        for (int e = 0; e < NE; e++) if (e != a1 && acc[e] > acc[a2]) a2 = e;
        float p2 = __expf(acc[a2] - acc[a1]);
        float s = 1.f + p2;
        picke[t * 2] = a1;  picke[t * 2 + 1] = a2;
        pickw[t * 2] = 1.f / s;  pickw[t * 2 + 1] = p2 / s;
        atomicAdd(&meta[a1], 1);
        atomicAdd(&meta[a2], 1);
    }
}

// ---------------- schedule: 256-padded segment offsets + default fill ----------------
__global__ void sched_k(int* meta, int* perm, float* wsort) {
    if (threadIdx.x == 0) {
        int o = 0;
        for (int e = 0; e < NE; e++) {
            meta[16 + e] = o;
            o += ((meta[e] + 255) / 256) * 256;
        }
        meta[16 + NE] = o;
        meta[25] = o;
        meta[26] = o / 128;
        meta[27] = o / 256;
    }
    for (int i = threadIdx.x; i < MAX_ROWS; i += 256) { perm[i] = -1; wsort[i] = 0.f; }
}

// ---------------- scatter: sorted (token,slot) list ----------------
__global__ void scatter_k(int* meta, const int* __restrict__ picke,
                          const float* __restrict__ pickw,
                          int* __restrict__ perm, float* __restrict__ wsort) {
    int t = blockIdx.x * 256 + threadIdx.x;
#pragma unroll
    for (int k = 0; k < 2; k++) {
        int e = picke[t * 2 + k];
        int pos = meta[16 + e] + atomicAdd(&meta[8 + e], 1);
        perm[pos] = t * 2 + k;
        wsort[pos] = pickw[t * 2 + k];
    }
}

// ---------------- GEMM1: 256x256 8-phase counted-vmcnt schedule ----------------
// h = silu(X W1) * (X W3) via fused interleaved w13t; gathered A rows.
// LDS: toks(1KB) | A0(32KB) | A1(32KB) | B0(32KB) | B1(32KB) = 132096 B
// K-tile V: phases stage A0(V+1)@ph0, A1(V+1)@ph1, B0(V+2)@ph2, B1(V+2)@ph3;
// vmcnt(4) once per K-tile (steady), vmcnt(0) only at the final boundary.

#define G1_STAGE_A(dstbuf, h, kt) do { \
    gl_lds16(xb + asrc[h][0] + (u32)(kt) * 128u, (dstbuf) + (h) * 16384 + wave * 2048); \
    gl_lds16(xb + asrc[h][1] + (u32)(kt) * 128u, (dstbuf) + (h) * 16384 + wave * 2048 + 1024); \
} while (0)
#define G1_STAGE_B(dstbuf, h, kt) do { \
    gl_lds16(wbs + bsrc[h][0] + (u32)(kt) * 128u, (dstbuf) + (h) * 16384 + wave * 2048); \
    gl_lds16(wbs + bsrc[h][1] + (u32)(kt) * 128u, (dstbuf) + (h) * 16384 + wave * 2048 + 1024); \
} while (0)
#define G1_RDA(buf, m, kk) (*(const bf16x8*)((buf) + arow + (m) * 2048 + ((kk) ? cs1 : cs0)))
#define G1_RDB(buf, jn, kk) (*(const bf16x8*)((buf) + brow + (jn) * 2048 + ((kk) ? cs1 : cs0)))

__launch_bounds__(512, 2)
__global__ void gemm1_k(const u16* __restrict__ x, const u16* __restrict__ w13t,
                        u16* __restrict__ hbuf, const int* __restrict__ meta,
                        const int* __restrict__ perm) {
    int rb = blockIdx.y;
    if (rb >= meta[27]) return;
    int nb = blockIdx.x;                 // 0..31 (N13/256)
    int row0 = rb * 256;
    int e = 0;
#pragma unroll
    for (int i = 1; i < NE; i++) if (row0 >= meta[16 + i]) e = i;

    extern __shared__ char smem[];
    int* toks = (int*)smem;
    char* Ab0 = smem + 1024;
    char* Ab1 = Ab0 + 32768;
    char* Bb0 = Ab1 + 32768;
    char* Bb1 = Bb0 + 32768;

    int tid = threadIdx.x;
    if (tid < 256) { int p = perm[row0 + tid]; toks[tid] = (p < 0) ? 0 : (p >> 1); }
    __syncthreads();

    int wave = tid >> 6, lane = tid & 63;
    int l16 = lane & 15, quad = lane >> 4;
    int wm = wave >> 2, wn4 = wave & 3;  // 2M x 4N wave grid; per-wave out = 128x64
    int lr = lane >> 3;                  // 0..7: row within an 8-row staging call
    int csw = ((lane & 7) ^ lr) * 16;    // pre-swizzled global chunk (linear LDS dest)

    const char* xb  = (const char*)x;
    const char* wbs = (const char*)w13t + (size_t)e * N13 * H_DIM * 2;
    u32 asrc[2][2], bsrc[2][2];          // byte offsets excluding kt*128
#pragma unroll
    for (int h = 0; h < 2; h++)
#pragma unroll
        for (int j = 0; j < 2; j++) {
            int r = h * 128 + wave * 16 + j * 8 + lr;
            asrc[h][j] = (u32)toks[r] * 2048u + csw;
            bsrc[h][j] = (u32)(nb * 256 + r) * 2048u + csw;
        }

    // fragment read offsets: row-major [256][64] bf16, chunk ^= (row&7) swizzle
    int cs0 = (quad ^ (l16 & 7)) * 16;
    int cs1 = ((4 + quad) ^ (l16 & 7)) * 16;
    int arow = (wm * 128 + l16) * 128;
    int brow = (wn4 * 64 + l16) * 128;

    f32x4 acc[8][4];
    f32x4 zero = {0.f, 0.f, 0.f, 0.f};
#pragma unroll
    for (int m = 0; m < 8; m++)
#pragma unroll
        for (int j = 0; j < 4; j++) acc[m][j] = zero;

    // prologue: tile0 (A+B) + tile1 B; leave tile1's B (4 loads) in flight
    G1_STAGE_A(Ab0, 0, 0); G1_STAGE_A(Ab0, 1, 0);
    G1_STAGE_B(Bb0, 0, 0); G1_STAGE_B(Bb0, 1, 0);
    G1_STAGE_B(Bb1, 0, 1); G1_STAGE_B(Bb1, 1, 1);
    asm volatile("s_waitcnt vmcnt(4)" ::: "memory");
    __builtin_amdgcn_s_barrier();

    for (int V = 0; V < G1_NKT; ++V) {
        char* Ap = (V & 1) ? Ab1 : Ab0;
        char* Aq = (V & 1) ? Ab0 : Ab1;
        char* Bp = (V & 1) ? Bb1 : Bb0;   // B buffer of tile V == buffer of tile V+2
        int t1 = V + 1, t2 = V + 2;
        bf16x8 bfr[4][2];
#pragma unroll
        for (int ph = 0; ph < 4; ++ph) {
            if (ph == 0) {
#pragma unroll
                for (int jn = 0; jn < 4; jn++) {
                    bfr[jn][0] = G1_RDB(Bp, jn, 0);
                    bfr[jn][1] = G1_RDB(Bp, jn, 1);
                }
            }
            bf16x8 af[2][2];
            af[0][0] = G1_RDA(Ap, 2 * ph, 0);
            af[0][1] = G1_RDA(Ap, 2 * ph, 1);
            af[1][0] = G1_RDA(Ap, 2 * ph + 1, 0);
            af[1][1] = G1_RDA(Ap, 2 * ph + 1, 1);
            if (ph == 0 && t1 < G1_NKT) G1_STAGE_A(Aq, 0, t1);
            if (ph == 1 && t1 < G1_NKT) G1_STAGE_A(Aq, 1, t1);
            if (ph == 2 && t2 < G1_NKT) G1_STAGE_B(Bp, 0, t2);
            if (ph == 3 && t2 < G1_NKT) G1_STAGE_B(Bp, 1, t2);
            __builtin_amdgcn_s_barrier();
            asm volatile("s_waitcnt lgkmcnt(0)" ::: "memory");
            __builtin_amdgcn_s_setprio(1);
#pragma unroll
            for (int s = 0; s < 2; s++)
#pragma unroll
                for (int jn = 0; jn < 4; jn++)
#pragma unroll
                    for (int kk = 0; kk < 2; kk++)
                        acc[2 * ph + s][jn] = __builtin_amdgcn_mfma_f32_16x16x32_bf16(
                            af[s][kk], bfr[jn][kk], acc[2 * ph + s][jn], 0, 0, 0);
            __builtin_amdgcn_s_setprio(0);
            if (ph == 3) {
                if (t2 < G1_NKT)      asm volatile("s_waitcnt vmcnt(4)" ::: "memory");
                else if (t1 < G1_NKT) asm volatile("s_waitcnt vmcnt(0)" ::: "memory");
            }
            __builtin_amdgcn_s_barrier();
        }
    }

    // epilogue: silu(w1-part) * w3-part; frags jn and jn+2 are the paired columns
#pragma unroll
    for (int m = 0; m < 8; m++) {
#pragma unroll
        for (int jn = 0; jn < 2; jn++) {
            f32x4 c1 = acc[m][jn], c3 = acc[m][jn + 2];
#pragma unroll
            for (int r = 0; r < 4; r++) {
                float v1 = c1[r];
                float hv = v1 / (1.f + __expf(-v1)) * c3[r];
                int rl = wm * 128 + m * 16 + quad * 4 + r;
                int col = nb * 128 + wn4 * 32 + jn * 16 + l16;
                hbuf[(size_t)(row0 + rl) * FFN_DIM + col] = f2bf(hv);
            }
        }
    }
}

// ---------------- GEMM2: ypart = weight * (h W2), scattered fp32 (unchanged) ----------------
__launch_bounds__(256, 2)
__global__ void gemm2_k(const u16* __restrict__ hbuf, const u16* __restrict__ w2t,
                        float* __restrict__ ypart, const int* __restrict__ meta,
                        const int* __restrict__ perm, const float* __restrict__ wsort) {
    int rb = blockIdx.y;
    if (rb >= meta[26]) return;
    int nb = blockIdx.x;  // 0..7
    int row0 = rb * BM;
    int e = 0;
#pragma unroll
    for (int i = 1; i < NE; i++) if (row0 >= meta[16 + i]) e = i;

    __shared__ u16 As[BM * BK], Bs[BN * BK];
    __shared__ int pe[BM];
    __shared__ float pw[BM];
    int tid = threadIdx.x;
    if (tid < BM) { pe[tid] = perm[row0 + tid]; pw[tid] = wsort[row0 + tid]; }
    __syncthreads();

    int ar0 = tid >> 2, as0 = tid & 3;
    int ar1 = ar0 + 64;
    const u16* aptr0 = hbuf + (size_t)(row0 + ar0) * FFN_DIM + as0 * 8;
    const u16* aptr1 = hbuf + (size_t)(row0 + ar1) * FFN_DIM + as0 * 8;
    const u16* wb = w2t + (size_t)e * H_DIM * FFN_DIM + (size_t)(nb * BN) * FFN_DIM;
    const u16* bp0 = wb + (size_t)ar0 * FFN_DIM + as0 * 8;
    const u16* bp1 = wb + (size_t)ar1 * FFN_DIM + as0 * 8;

    int aw0 = ar0 * BK + ((as0 ^ ((ar0 >> 1) & 3)) * 8);
    int aw1 = ar1 * BK + ((as0 ^ ((ar1 >> 1) & 3)) * 8);

    int wave = tid >> 6, lane = tid & 63, quad = lane >> 4, l16 = lane & 15;
    int wm = (wave >> 1) * 64, wn = (wave & 1) * 64;
    int aoff[4], boff[4];
#pragma unroll
    for (int i = 0; i < 4; i++) { int r = wm + i * 16 + l16; aoff[i] = r * BK + ((quad ^ ((r >> 1) & 3)) * 8); }
#pragma unroll
    for (int j = 0; j < 4; j++) { int n = wn + j * 16 + l16; boff[j] = n * BK + ((quad ^ ((n >> 1) & 3)) * 8); }

    f32x4 acc[4][4];
    f32x4 zero = {0.f, 0.f, 0.f, 0.f};
#pragma unroll
    for (int i = 0; i < 4; i++)
#pragma unroll
        for (int j = 0; j < 4; j++) acc[i][j] = zero;

    for (int k0 = 0; k0 < FFN_DIM; k0 += BK) {
        u16x8 a0 = *(const u16x8*)(aptr0 + k0);
        u16x8 a1 = *(const u16x8*)(aptr1 + k0);
        u16x8 b0 = *(const u16x8*)(bp0 + k0);
        u16x8 b1v = *(const u16x8*)(bp1 + k0);
        __syncthreads();
        *(u16x8*)&As[aw0] = a0; *(u16x8*)&As[aw1] = a1;
        *(u16x8*)&Bs[aw0] = b0; *(u16x8*)&Bs[aw1] = b1v;
        __syncthreads();
        bf16x8 af[4];
#pragma unroll
        for (int i = 0; i < 4; i++) af[i] = *(const bf16x8*)&As[aoff[i]];
#pragma unroll
        for (int jn = 0; jn < 4; jn++) {
            bf16x8 bf = *(const bf16x8*)&Bs[boff[jn]];
#pragma unroll
            for (int i = 0; i < 4; i++)
                acc[i][jn] = __builtin_amdgcn_mfma_f32_16x16x32_bf16(af[i], bf, acc[i][jn], 0, 0, 0);
        }
    }
#pragma unroll
    for (int i = 0; i < 4; i++)
#pragma unroll
        for (int jn = 0; jn < 4; jn++) {
            f32x4 c = acc[i][jn];
#pragma unroll
            for (int r = 0; r < 4; r++) {
                int rloc = wm + i * 16 + quad * 4 + r;
                int p = pe[rloc];
                if (p >= 0) {
                    int col = nb * BN + wn + jn * 16 + l16;
                    ypart[(size_t)p * H_DIM + col] = c[r] * pw[rloc];
                }
            }
        }
}

// ---------------- combine the two expert slots per token (fp32) ----------------
__global__ void combine_k(const float* __restrict__ ypart, float* __restrict__ y) {
    int c = blockIdx.x * 256 + threadIdx.x;   // one f32x4 per thread; T*H/4 total
    int t = c >> 8, cc = c & 255;             // H/4 = 256 chunks per row
    f32x4 a = *(const f32x4*)(ypart + (size_t)(t * 2) * H_DIM + cc * 4);
    f32x4 b = *(const f32x4*)(ypart + (size_t)(t * 2 + 1) * H_DIM + cc * 4);
    f32x4 o = a + b;
    *(f32x4*)(y + (size_t)t * H_DIM + cc * 4) = o;
}

extern "C" void kernel_launch(void* const* d_in, const int* in_sizes, int n_in,
                              void* d_out, int out_size, void* d_ws, size_t ws_size,
                              hipStream_t stream) {
    (void)in_sizes; (void)n_in; (void)out_size; (void)ws_size;
    const float* x  = (const float*)d_in[0];
    const float* gw = (const float*)d_in[1];
    const float* w1 = (const float*)d_in[2];
    const float* w2 = (const float*)d_in[3];
    const float* w3 = (const float*)d_in[4];
    float* out = (float*)d_out;
    char* ws = (char*)d_ws;

    int*   meta  = (int*)(ws + META_OFF);
    int*   picke = (int*)(ws + PICKE_OFF);
    float* pickw = (float*)(ws + PICKW_OFF);
    int*   perm  = (int*)(ws + PERM_OFF);
    float* wsort = (float*)(ws + WSORT_OFF);
    u16*   xbf   = (u16*)(ws + XBF_OFF);
    u16*   w13t  = (u16*)(ws + W13T_OFF);
    u16*   w2t   = (u16*)(ws + W2T_OFF);
    u16*   hbuf  = (u16*)(ws + HBUF_OFF);
    float* ypart = (float*)(ws + YPART_OFF);

    hipFuncSetAttribute((const void*)gemm1_k,
                        hipFuncAttributeMaxDynamicSharedMemorySize, G1_SMEM);

    init_k<<<1, 256, 0, stream>>>(meta);
    cvt_x_k<<<T_TOK * H_DIM / 8 / 256, 256, 0, stream>>>(x, xbf);
    transpose_cvt_w13_k<<<dim3(FFN_DIM / 64, H_DIM / 64, NE), 256, 0, stream>>>(w1, w13t, 0);
    transpose_cvt_w13_k<<<dim3(FFN_DIM / 64, H_DIM / 64, NE), 256, 0, stream>>>(w3, w13t, 1);
    transpose_cvt_k<<<dim3(H_DIM / 64, FFN_DIM / 64, NE), 256, 0, stream>>>(w2, w2t, FFN_DIM, H_DIM);
    router_k<<<T_TOK / 4, 256, 0, stream>>>(x, gw, out + (size_t)T_TOK * H_DIM, meta, picke, pickw);
    sched_k<<<1, 256, 0, stream>>>(meta, perm, wsort);
    scatter_k<<<T_TOK / 256, 256, 0, stream>>>(meta, picke, pickw, perm, wsort);
    gemm1_k<<<dim3(N13 / 256, MAX_RB256), 512, G1_SMEM, stream>>>(xbf, w13t, hbuf, meta, perm);
    gemm2_k<<<dim3(H_DIM / BN, MAX_RB128), 256, 0, stream>>>(hbuf, w2t, ypart, meta, perm, wsort);
    combine_k<<<T_TOK * H_DIM / 4 / 256, 256, 0, stream>>>(ypart, out);
}

// Round 2
// 1207.417 us; speedup vs baseline: 1.0979x; 1.0442x over previous
//
#include <hip/hip_runtime.h>
#include <hip/hip_bf16.h>

// ---------------- problem constants ----------------
#define T_TOK   8192
#define H_DIM   1024
#define FFN_DIM 4096
#define NE      8
#define N13     (2 * FFN_DIM)            // 8192 fused [w1|w3] columns (interleaved)

// gemm1/gemm2 8-phase tile
#define G1_BK   64
#define G1_NKT  (H_DIM / G1_BK)          // 16
#define G1_SMEM (1024 + 131072)          // toks + 2x(A 32KB) + 2x(B 32KB)
#define G2_NKT  (FFN_DIM / G1_BK)        // 64
#define G2_SMEM (2048 + 131072)          // pe+pw + 2x(A 32KB) + 2x(B 32KB)

#define MAX_RB256 (T_TOK * 2 / 256 + NE) // 72
#define MAX_ROWS  (MAX_RB256 * 256)      // 18432

typedef unsigned short u16;
typedef unsigned int   u32;
typedef u16   u16x8  __attribute__((ext_vector_type(8)));
typedef __bf16 bf16x8 __attribute__((ext_vector_type(8)));
typedef float f32x4  __attribute__((ext_vector_type(4)));

// ---------------- workspace layout (bytes) ----------------
// meta ints: [0..7] counts, [8..15] fill, [16..24] padded offsets (256-granular),
//            [25] total_rows, [26] rb128 count, [27] rb256 count
#define META_OFF   ((size_t)0)
#define PICKE_OFF  ((size_t)1024)
#define PICKW_OFF  (PICKE_OFF + (size_t)T_TOK * 2 * 4)
#define PERM_OFF   (PICKW_OFF + (size_t)T_TOK * 2 * 4)
#define WSORT_OFF  (PERM_OFF  + (size_t)MAX_ROWS * 4)
#define XBF_OFF    (WSORT_OFF + (size_t)MAX_ROWS * 4)               // 279552
#define W13T_OFF   (XBF_OFF + (size_t)T_TOK * H_DIM * 2)            // +16 MB
#define W2T_OFF    (W13T_OFF + (size_t)NE * N13 * H_DIM * 2)        // +128 MB
#define HBUF_OFF   (W2T_OFF + (size_t)NE * FFN_DIM * H_DIM * 2)     // +64 MB
#define YPART_OFF  W13T_OFF   // alias: w13t (128MB) dead after gemm1; ypart fp32 (67MB)

__device__ __forceinline__ u16 f2bf(float f) {
    unsigned u = __builtin_bit_cast(unsigned, f);
    unsigned r = u + 0x7fffu + ((u >> 16) & 1u);   // RNE
    return (u16)(r >> 16);
}

// async global->LDS, 16B per lane, dest = wave-uniform base + lane*16
__device__ __forceinline__ void gl_lds16(const void* g, void* l) {
    __builtin_amdgcn_global_load_lds((const __attribute__((address_space(1))) u32*)g,
                                     (__attribute__((address_space(3))) u32*)l,
                                     16, 0, 0);
}

// ---------------- tiny init ----------------
__global__ void init_k(int* meta) {
    if (threadIdx.x < 256) meta[threadIdx.x] = 0;
}

// ---------------- x: fp32 -> bf16, same layout ----------------
__global__ void cvt_x_k(const float* __restrict__ src, u16* __restrict__ dst) {
    int i = blockIdx.x * 256 + threadIdx.x;   // one u16x8 per thread
    f32x4 a = *(const f32x4*)(src + (size_t)i * 8);
    f32x4 b = *(const f32x4*)(src + (size_t)i * 8 + 4);
    u16x8 o;
#pragma unroll
    for (int j = 0; j < 4; j++) { o[j] = f2bf(a[j]); o[4 + j] = f2bf(b[j]); }
    *(u16x8*)(dst + (size_t)i * 8) = o;
}

// ---------------- transpose+convert for w2: dst_bf16[C][R] = src_f32[R][C] ----------------
__global__ void transpose_cvt_k(const float* __restrict__ src, u16* __restrict__ dst, int R, int C) {
    __shared__ u16 Lt[64 * 72];
    int bx = blockIdx.x, by = blockIdx.y, e = blockIdx.z;
    const float* s = src + (size_t)e * R * C + (size_t)(by * 64) * C + bx * 64;
    u16* d = dst + (size_t)e * R * C + (size_t)(bx * 64) * R + by * 64;
    int tid = threadIdx.x;
#pragma unroll
    for (int o = tid; o < 512; o += 256) {
        int r = o >> 3, cc = o & 7;
        const float* sp = s + (size_t)r * C + cc * 8;
        f32x4 f0 = *(const f32x4*)sp;
        f32x4 f1 = *(const f32x4*)(sp + 4);
        u16x8 v;
#pragma unroll
        for (int j = 0; j < 4; j++) { v[j] = f2bf(f0[j]); v[4 + j] = f2bf(f1[j]); }
        int cs = (cc ^ ((r >> 3) & 7)) & 7;
        *(u16x8*)&Lt[r * 72 + cs * 8] = v;
    }
    __syncthreads();
#pragma unroll
    for (int o = tid; o < 512; o += 256) {
        int cl = o >> 3, rc = o & 7;
        u16x8 w;
#pragma unroll
        for (int j = 0; j < 8; j++) {
            int rr = rc * 8 + j;
            w[j] = Lt[rr * 72 + ((((cl >> 3) ^ rc) & 7) * 8) + (cl & 7)];
        }
        *(u16x8*)(d + (size_t)cl * R + rc * 8) = w;
    }
}

// ---------------- transpose+convert w1/w3 -> interleaved w13t[e][n'][k] ----------------
// n' layout: per 256-col supertile nb: 4 wave-blocks of 64 = [32 w1-cols | 32 w3-cols]
// n'(c, which) = (c>>7)*256 + ((c>>5)&3)*64 + which*32 + (c&31)
__global__ void transpose_cvt_w13_k(const float* __restrict__ src, u16* __restrict__ dst, int which) {
    __shared__ u16 Lt[64 * 72];
    int bx = blockIdx.x, by = blockIdx.y, e = blockIdx.z;
    const float* s = src + (size_t)e * H_DIM * FFN_DIM + (size_t)(by * 64) * FFN_DIM + bx * 64;
    u16* d = dst + (size_t)e * N13 * H_DIM;
    int tid = threadIdx.x;
#pragma unroll
    for (int o = tid; o < 512; o += 256) {
        int r = o >> 3, cc = o & 7;
        const float* sp = s + (size_t)r * FFN_DIM + cc * 8;
        f32x4 f0 = *(const f32x4*)sp;
        f32x4 f1 = *(const f32x4*)(sp + 4);
        u16x8 v;
#pragma unroll
        for (int j = 0; j < 4; j++) { v[j] = f2bf(f0[j]); v[4 + j] = f2bf(f1[j]); }
        int cs = (cc ^ ((r >> 3) & 7)) & 7;
        *(u16x8*)&Lt[r * 72 + cs * 8] = v;
    }
    __syncthreads();
#pragma unroll
    for (int o = tid; o < 512; o += 256) {
        int cl = o >> 3, rc = o & 7;
        u16x8 w;
#pragma unroll
        for (int j = 0; j < 8; j++) {
            int rr = rc * 8 + j;
            w[j] = Lt[rr * 72 + ((((cl >> 3) ^ rc) & 7) * 8) + (cl & 7)];
        }
        int c = bx * 64 + cl;
        int np = ((c >> 7) << 8) | (((c >> 5) & 3) << 6) | (which << 5) | (c & 31);
        *(u16x8*)(d + (size_t)np * H_DIM + by * 64 + rc * 8) = w;
    }
}

// ---------------- router: fp32 logits, top-2, picks ----------------
__global__ void router_k(const float* __restrict__ x, const float* __restrict__ gw,
                         float* __restrict__ out_logits, int* __restrict__ meta,
                         int* __restrict__ picke, float* __restrict__ pickw) {
    __shared__ float G[NE * H_DIM];   // 32 KB
    int tid = threadIdx.x;
#pragma unroll
    for (int o = tid; o < 2048; o += 256)
        *(f32x4*)&G[o * 4] = *(const f32x4*)(gw + o * 4);
    __syncthreads();

    int wave = tid >> 6, lane = tid & 63;
    int t = blockIdx.x * 4 + wave;
    const float* xr = x + (size_t)t * H_DIM + lane * 16;
    f32x4 v0 = *(const f32x4*)xr,       v1 = *(const f32x4*)(xr + 4);
    f32x4 v2 = *(const f32x4*)(xr + 8), v3 = *(const f32x4*)(xr + 12);

    float acc[NE];
#pragma unroll
    for (int e = 0; e < NE; e++) {
        const float* gr = &G[e * H_DIM + lane * 16];
        f32x4 g0 = *(const f32x4*)gr,       g1 = *(const f32x4*)(gr + 4);
        f32x4 g2 = *(const f32x4*)(gr + 8), g3 = *(const f32x4*)(gr + 12);
        float a = 0.f;
#pragma unroll
        for (int j = 0; j < 4; j++) {
            a += v0[j] * g0[j]; a += v1[j] * g1[j];
            a += v2[j] * g2[j]; a += v3[j] * g3[j];
        }
        acc[e] = a;
    }
#pragma unroll
    for (int e = 0; e < NE; e++)
#pragma unroll
        for (int off = 32; off > 0; off >>= 1) acc[e] += __shfl_xor(acc[e], off);

    if (lane < NE) out_logits[(size_t)t * NE + lane] = acc[lane];
    if (lane == 0) {
        int a1 = 0;
#pragma unroll
        for (int e = 1; e < NE; e++) if (acc[e] > acc[a1]) a1 = e;
        int a2 = (a1 == 0) ? 1 : 0;
#pragma unroll
        for (int e = 0; e < NE; e++) if (e != a1 && acc[e] > acc[a2]) a2 = e;
        float p2 = __expf(acc[a2] - acc[a1]);
        float s = 1.f + p2;
        picke[t * 2] = a1;  picke[t * 2 + 1] = a2;
        pickw[t * 2] = 1.f / s;  pickw[t * 2 + 1] = p2 / s;
        atomicAdd(&meta[a1], 1);
        atomicAdd(&meta[a2], 1);
    }
}

// ---------------- schedule: 256-padded segment offsets + default fill ----------------
__global__ void sched_k(int* meta, int* perm, float* wsort) {
    if (threadIdx.x == 0) {
        int o = 0;
        for (int e = 0; e < NE; e++) {
            meta[16 + e] = o;
            o += ((meta[e] + 255) / 256) * 256;
        }
        meta[16 + NE] = o;
        meta[25] = o;
        meta[26] = o / 128;
        meta[27] = o / 256;
    }
    for (int i = threadIdx.x; i < MAX_ROWS; i += 256) { perm[i] = -1; wsort[i] = 0.f; }
}

// ---------------- scatter: sorted (token,slot) list ----------------
__global__ void scatter_k(int* meta, const int* __restrict__ picke,
                          const float* __restrict__ pickw,
                          int* __restrict__ perm, float* __restrict__ wsort) {
    int t = blockIdx.x * 256 + threadIdx.x;
#pragma unroll
    for (int k = 0; k < 2; k++) {
        int e = picke[t * 2 + k];
        int pos = meta[16 + e] + atomicAdd(&meta[8 + e], 1);
        perm[pos] = t * 2 + k;
        wsort[pos] = pickw[t * 2 + k];
    }
}

// ---------------- GEMM1: 256x256 8-phase counted-vmcnt schedule ----------------
// h = silu(X W1) * (X W3) via fused interleaved w13t; gathered A rows.
// LDS: toks(1KB) | A0(32KB) | A1(32KB) | B0(32KB) | B1(32KB) = 132096 B
// K-tile V: phases stage A0(V+1)@ph0, A1(V+1)@ph1, B0(V+2)@ph2, B1(V+2)@ph3;
// vmcnt(4) once per K-tile (steady), vmcnt(0) only at the final boundary.

#define G1_STAGE_A(dstbuf, h, kt) do { \
    gl_lds16(xb + asrc[h][0] + (u32)(kt) * 128u, (dstbuf) + (h) * 16384 + wave * 2048); \
    gl_lds16(xb + asrc[h][1] + (u32)(kt) * 128u, (dstbuf) + (h) * 16384 + wave * 2048 + 1024); \
} while (0)
#define G1_STAGE_B(dstbuf, h, kt) do { \
    gl_lds16(wbs + bsrc[h][0] + (u32)(kt) * 128u, (dstbuf) + (h) * 16384 + wave * 2048); \
    gl_lds16(wbs + bsrc[h][1] + (u32)(kt) * 128u, (dstbuf) + (h) * 16384 + wave * 2048 + 1024); \
} while (0)
#define G1_RDA(buf, m, kk) (*(const bf16x8*)((buf) + arow + (m) * 2048 + ((kk) ? cs1 : cs0)))
#define G1_RDB(buf, jn, kk) (*(const bf16x8*)((buf) + brow + (jn) * 2048 + ((kk) ? cs1 : cs0)))

__launch_bounds__(512, 2)
__global__ void gemm1_k(const u16* __restrict__ x, const u16* __restrict__ w13t,
                        u16* __restrict__ hbuf, const int* __restrict__ meta,
                        const int* __restrict__ perm) {
    int rb = blockIdx.y;
    if (rb >= meta[27]) return;
    int nb = blockIdx.x;                 // 0..31 (N13/256)
    int row0 = rb * 256;
    int e = 0;
#pragma unroll
    for (int i = 1; i < NE; i++) if (row0 >= meta[16 + i]) e = i;

    extern __shared__ char smem[];
    int* toks = (int*)smem;
    char* Ab0 = smem + 1024;
    char* Ab1 = Ab0 + 32768;
    char* Bb0 = Ab1 + 32768;
    char* Bb1 = Bb0 + 32768;

    int tid = threadIdx.x;
    if (tid < 256) { int p = perm[row0 + tid]; toks[tid] = (p < 0) ? 0 : (p >> 1); }
    __syncthreads();

    int wave = tid >> 6, lane = tid & 63;
    int l16 = lane & 15, quad = lane >> 4;
    int wm = wave >> 2, wn4 = wave & 3;  // 2M x 4N wave grid; per-wave out = 128x64
    int lr = lane >> 3;                  // 0..7: row within an 8-row staging call
    int csw = ((lane & 7) ^ lr) * 16;    // pre-swizzled global chunk (linear LDS dest)

    const char* xb  = (const char*)x;
    const char* wbs = (const char*)w13t + (size_t)e * N13 * H_DIM * 2;
    u32 asrc[2][2], bsrc[2][2];          // byte offsets excluding kt*128
#pragma unroll
    for (int h = 0; h < 2; h++)
#pragma unroll
        for (int j = 0; j < 2; j++) {
            int r = h * 128 + wave * 16 + j * 8 + lr;
            asrc[h][j] = (u32)toks[r] * 2048u + csw;
            bsrc[h][j] = (u32)(nb * 256 + r) * 2048u + csw;
        }

    // fragment read offsets: row-major [256][64] bf16, chunk ^= (row&7) swizzle
    int cs0 = (quad ^ (l16 & 7)) * 16;
    int cs1 = ((4 + quad) ^ (l16 & 7)) * 16;
    int arow = (wm * 128 + l16) * 128;
    int brow = (wn4 * 64 + l16) * 128;

    f32x4 acc[8][4];
    f32x4 zero = {0.f, 0.f, 0.f, 0.f};
#pragma unroll
    for (int m = 0; m < 8; m++)
#pragma unroll
        for (int j = 0; j < 4; j++) acc[m][j] = zero;

    // prologue: tile0 (A+B) + tile1 B; leave tile1's B (4 loads) in flight
    G1_STAGE_A(Ab0, 0, 0); G1_STAGE_A(Ab0, 1, 0);
    G1_STAGE_B(Bb0, 0, 0); G1_STAGE_B(Bb0, 1, 0);
    G1_STAGE_B(Bb1, 0, 1); G1_STAGE_B(Bb1, 1, 1);
    asm volatile("s_waitcnt vmcnt(4)" ::: "memory");
    __builtin_amdgcn_s_barrier();

    for (int V = 0; V < G1_NKT; ++V) {
        char* Ap = (V & 1) ? Ab1 : Ab0;
        char* Aq = (V & 1) ? Ab0 : Ab1;
        char* Bp = (V & 1) ? Bb1 : Bb0;   // B buffer of tile V == buffer of tile V+2
        int t1 = V + 1, t2 = V + 2;
        bf16x8 bfr[4][2];
#pragma unroll
        for (int ph = 0; ph < 4; ++ph) {
            if (ph == 0) {
#pragma unroll
                for (int jn = 0; jn < 4; jn++) {
                    bfr[jn][0] = G1_RDB(Bp, jn, 0);
                    bfr[jn][1] = G1_RDB(Bp, jn, 1);
                }
            }
            bf16x8 af[2][2];
            af[0][0] = G1_RDA(Ap, 2 * ph, 0);
            af[0][1] = G1_RDA(Ap, 2 * ph, 1);
            af[1][0] = G1_RDA(Ap, 2 * ph + 1, 0);
            af[1][1] = G1_RDA(Ap, 2 * ph + 1, 1);
            if (ph == 0 && t1 < G1_NKT) G1_STAGE_A(Aq, 0, t1);
            if (ph == 1 && t1 < G1_NKT) G1_STAGE_A(Aq, 1, t1);
            if (ph == 2 && t2 < G1_NKT) G1_STAGE_B(Bp, 0, t2);
            if (ph == 3 && t2 < G1_NKT) G1_STAGE_B(Bp, 1, t2);
            __builtin_amdgcn_s_barrier();
            asm volatile("s_waitcnt lgkmcnt(0)" ::: "memory");
            __builtin_amdgcn_s_setprio(1);
#pragma unroll
            for (int s = 0; s < 2; s++)
#pragma unroll
                for (int jn = 0; jn < 4; jn++)
#pragma unroll
                    for (int kk = 0; kk < 2; kk++)
                        acc[2 * ph + s][jn] = __builtin_amdgcn_mfma_f32_16x16x32_bf16(
                            af[s][kk], bfr[jn][kk], acc[2 * ph + s][jn], 0, 0, 0);
            __builtin_amdgcn_s_setprio(0);
            if (ph == 3) {
                if (t2 < G1_NKT)      asm volatile("s_waitcnt vmcnt(4)" ::: "memory");
                else if (t1 < G1_NKT) asm volatile("s_waitcnt vmcnt(0)" ::: "memory");
            }
            __builtin_amdgcn_s_barrier();
        }
    }

    // epilogue: silu(w1-part) * w3-part; frags jn and jn+2 are the paired columns
#pragma unroll
    for (int m = 0; m < 8; m++) {
#pragma unroll
        for (int jn = 0; jn < 2; jn++) {
            f32x4 c1 = acc[m][jn], c3 = acc[m][jn + 2];
#pragma unroll
            for (int r = 0; r < 4; r++) {
                float v1 = c1[r];
                float hv = v1 / (1.f + __expf(-v1)) * c3[r];
                int rl = wm * 128 + m * 16 + quad * 4 + r;
                int col = nb * 128 + wn4 * 32 + jn * 16 + l16;
                hbuf[(size_t)(row0 + rl) * FFN_DIM + col] = f2bf(hv);
            }
        }
    }
}

// ---------------- GEMM2: 256x256 8-phase counted-vmcnt schedule ----------------
// ypart[p] = pw * (hbuf W2); A = dense hbuf rows (row stride 8192B), B = w2t[e]
// (col stride 8192B). K = FFN = 4096 -> 64 K-tiles, grid 4 x rb256 (~264 blocks,
// ~1 round/CU). LDS: pe(1KB) | pw(1KB) | A0|A1|B0|B1 (32KB each) = 133120 B.

#define G2_STAGE_A(dstbuf, h, kt) do { \
    gl_lds16(ab + asrc[h][0] + (u32)(kt) * 128u, (dstbuf) + (h) * 16384 + wave * 2048); \
    gl_lds16(ab + asrc[h][1] + (u32)(kt) * 128u, (dstbuf) + (h) * 16384 + wave * 2048 + 1024); \
} while (0)
#define G2_STAGE_B(dstbuf, h, kt) do { \
    gl_lds16(wbs + bsrc[h][0] + (u32)(kt) * 128u, (dstbuf) + (h) * 16384 + wave * 2048); \
    gl_lds16(wbs + bsrc[h][1] + (u32)(kt) * 128u, (dstbuf) + (h) * 16384 + wave * 2048 + 1024); \
} while (0)

__launch_bounds__(512, 2)
__global__ void gemm2_k(const u16* __restrict__ hbuf, const u16* __restrict__ w2t,
                        float* __restrict__ ypart, const int* __restrict__ meta,
                        const int* __restrict__ perm, const float* __restrict__ wsort) {
    int rb = blockIdx.y;
    if (rb >= meta[27]) return;
    int nb = blockIdx.x;                 // 0..3 (H_DIM/256)
    int row0 = rb * 256;
    int e = 0;
#pragma unroll
    for (int i = 1; i < NE; i++) if (row0 >= meta[16 + i]) e = i;

    extern __shared__ char smem[];
    int*   pe = (int*)smem;
    float* pw = (float*)(smem + 1024);
    char* Ab0 = smem + 2048;
    char* Ab1 = Ab0 + 32768;
    char* Bb0 = Ab1 + 32768;
    char* Bb1 = Bb0 + 32768;

    int tid = threadIdx.x;
    if (tid < 256) { pe[tid] = perm[row0 + tid]; pw[tid] = wsort[row0 + tid]; }

    int wave = tid >> 6, lane = tid & 63;
    int l16 = lane & 15, quad = lane >> 4;
    int wm = wave >> 2, wn4 = wave & 3;  // 2M x 4N wave grid; per-wave out = 128x64
    int lr = lane >> 3;
    int csw = ((lane & 7) ^ lr) * 16;

    const char* ab  = (const char*)hbuf;
    const char* wbs = (const char*)w2t + (size_t)e * H_DIM * FFN_DIM * 2;
    u32 asrc[2][2], bsrc[2][2];          // byte offsets excluding kt*128
#pragma unroll
    for (int h = 0; h < 2; h++)
#pragma unroll
        for (int j = 0; j < 2; j++) {
            int r = h * 128 + wave * 16 + j * 8 + lr;
            asrc[h][j] = (u32)(row0 + r) * 8192u + csw;   // hbuf row stride 4096*2B
            bsrc[h][j] = (u32)(nb * 256 + r) * 8192u + csw; // w2t col stride 4096*2B
        }

    int cs0 = (quad ^ (l16 & 7)) * 16;
    int cs1 = ((4 + quad) ^ (l16 & 7)) * 16;
    int arow = (wm * 128 + l16) * 128;
    int brow = (wn4 * 64 + l16) * 128;

    f32x4 acc[8][4];
    f32x4 zero = {0.f, 0.f, 0.f, 0.f};
#pragma unroll
    for (int m = 0; m < 8; m++)
#pragma unroll
        for (int j = 0; j < 4; j++) acc[m][j] = zero;

    // prologue
    G2_STAGE_A(Ab0, 0, 0); G2_STAGE_A(Ab0, 1, 0);
    G2_STAGE_B(Bb0, 0, 0); G2_STAGE_B(Bb0, 1, 0);
    G2_STAGE_B(Bb1, 0, 1); G2_STAGE_B(Bb1, 1, 1);
    asm volatile("s_waitcnt vmcnt(4)" ::: "memory");
    __builtin_amdgcn_s_barrier();

    for (int V = 0; V < G2_NKT; ++V) {
        char* Ap = (V & 1) ? Ab1 : Ab0;
        char* Aq = (V & 1) ? Ab0 : Ab1;
        char* Bp = (V & 1) ? Bb1 : Bb0;
        int t1 = V + 1, t2 = V + 2;
        bf16x8 bfr[4][2];
#pragma unroll
        for (int ph = 0; ph < 4; ++ph) {
            if (ph == 0) {
#pragma unroll
                for (int jn = 0; jn < 4; jn++) {
                    bfr[jn][0] = G1_RDB(Bp, jn, 0);
                    bfr[jn][1] = G1_RDB(Bp, jn, 1);
                }
            }
            bf16x8 af[2][2];
            af[0][0] = G1_RDA(Ap, 2 * ph, 0);
            af[0][1] = G1_RDA(Ap, 2 * ph, 1);
            af[1][0] = G1_RDA(Ap, 2 * ph + 1, 0);
            af[1][1] = G1_RDA(Ap, 2 * ph + 1, 1);
            if (ph == 0 && t1 < G2_NKT) G2_STAGE_A(Aq, 0, t1);
            if (ph == 1 && t1 < G2_NKT) G2_STAGE_A(Aq, 1, t1);
            if (ph == 2 && t2 < G2_NKT) G2_STAGE_B(Bp, 0, t2);
            if (ph == 3 && t2 < G2_NKT) G2_STAGE_B(Bp, 1, t2);
            __builtin_amdgcn_s_barrier();
            asm volatile("s_waitcnt lgkmcnt(0)" ::: "memory");
            __builtin_amdgcn_s_setprio(1);
#pragma unroll
            for (int s = 0; s < 2; s++)
#pragma unroll
                for (int jn = 0; jn < 4; jn++)
#pragma unroll
                    for (int kk = 0; kk < 2; kk++)
                        acc[2 * ph + s][jn] = __builtin_amdgcn_mfma_f32_16x16x32_bf16(
                            af[s][kk], bfr[jn][kk], acc[2 * ph + s][jn], 0, 0, 0);
            __builtin_amdgcn_s_setprio(0);
            if (ph == 3) {
                if (t2 < G2_NKT)      asm volatile("s_waitcnt vmcnt(4)" ::: "memory");
                else if (t1 < G2_NKT) asm volatile("s_waitcnt vmcnt(0)" ::: "memory");
            }
            __builtin_amdgcn_s_barrier();
        }
    }

    // epilogue: scattered weighted fp32 store
#pragma unroll
    for (int m = 0; m < 8; m++) {
#pragma unroll
        for (int jn = 0; jn < 4; jn++) {
            f32x4 c = acc[m][jn];
#pragma unroll
            for (int r = 0; r < 4; r++) {
                int rl = wm * 128 + m * 16 + quad * 4 + r;
                int p = pe[rl];
                if (p >= 0) {
                    int col = nb * 256 + wn4 * 64 + jn * 16 + l16;
                    ypart[(size_t)p * H_DIM + col] = c[r] * pw[rl];
                }
            }
        }
    }
}

// ---------------- combine the two expert slots per token (fp32) ----------------
__global__ void combine_k(const float* __restrict__ ypart, float* __restrict__ y) {
    int c = blockIdx.x * 256 + threadIdx.x;   // one f32x4 per thread; T*H/4 total
    int t = c >> 8, cc = c & 255;             // H/4 = 256 chunks per row
    f32x4 a = *(const f32x4*)(ypart + (size_t)(t * 2) * H_DIM + cc * 4);
    f32x4 b = *(const f32x4*)(ypart + (size_t)(t * 2 + 1) * H_DIM + cc * 4);
    f32x4 o = a + b;
    *(f32x4*)(y + (size_t)t * H_DIM + cc * 4) = o;
}

extern "C" void kernel_launch(void* const* d_in, const int* in_sizes, int n_in,
                              void* d_out, int out_size, void* d_ws, size_t ws_size,
                              hipStream_t stream) {
    (void)in_sizes; (void)n_in; (void)out_size; (void)ws_size;
    const float* x  = (const float*)d_in[0];
    const float* gw = (const float*)d_in[1];
    const float* w1 = (const float*)d_in[2];
    const float* w2 = (const float*)d_in[3];
    const float* w3 = (const float*)d_in[4];
    float* out = (float*)d_out;
    char* ws = (char*)d_ws;

    int*   meta  = (int*)(ws + META_OFF);
    int*   picke = (int*)(ws + PICKE_OFF);
    float* pickw = (float*)(ws + PICKW_OFF);
    int*   perm  = (int*)(ws + PERM_OFF);
    float* wsort = (float*)(ws + WSORT_OFF);
    u16*   xbf   = (u16*)(ws + XBF_OFF);
    u16*   w13t  = (u16*)(ws + W13T_OFF);
    u16*   w2t   = (u16*)(ws + W2T_OFF);
    u16*   hbuf  = (u16*)(ws + HBUF_OFF);
    float* ypart = (float*)(ws + YPART_OFF);

    hipFuncSetAttribute((const void*)gemm1_k,
                        hipFuncAttributeMaxDynamicSharedMemorySize, G1_SMEM);
    hipFuncSetAttribute((const void*)gemm2_k,
                        hipFuncAttributeMaxDynamicSharedMemorySize, G2_SMEM);

    init_k<<<1, 256, 0, stream>>>(meta);
    cvt_x_k<<<T_TOK * H_DIM / 8 / 256, 256, 0, stream>>>(x, xbf);
    transpose_cvt_w13_k<<<dim3(FFN_DIM / 64, H_DIM / 64, NE), 256, 0, stream>>>(w1, w13t, 0);
    transpose_cvt_w13_k<<<dim3(FFN_DIM / 64, H_DIM / 64, NE), 256, 0, stream>>>(w3, w13t, 1);
    transpose_cvt_k<<<dim3(H_DIM / 64, FFN_DIM / 64, NE), 256, 0, stream>>>(w2, w2t, FFN_DIM, H_DIM);
    router_k<<<T_TOK / 4, 256, 0, stream>>>(x, gw, out + (size_t)T_TOK * H_DIM, meta, picke, pickw);
    sched_k<<<1, 256, 0, stream>>>(meta, perm, wsort);
    scatter_k<<<T_TOK / 256, 256, 0, stream>>>(meta, picke, pickw, perm, wsort);
    gemm1_k<<<dim3(N13 / 256, MAX_RB256), 512, G1_SMEM, stream>>>(xbf, w13t, hbuf, meta, perm);
    gemm2_k<<<dim3(H_DIM / 256, MAX_RB256), 512, G2_SMEM, stream>>>(hbuf, w2t, ypart, meta, perm, wsort);
    combine_k<<<T_TOK * H_DIM / 4 / 256, 256, 0, stream>>>(ypart, out);
}